// Round 16
// baseline (2027.652 us; speedup 1.0000x reference)
//
#include <hip/hip_runtime.h>
#include <hip/hip_bf16.h>

// BasicLSTM: B=64, T=512, D=512, U=1024.  out = h_last [64][1024] f32.
// Round 16: R15 producers (verbatim) + 2-cohort pipelined consumer with
// tag-in-data h exchange (u32 = step<<16 | bf16h, proven R11).
//  - cohort A = rows [16mg,+8), B = [16mg+8,+16): independent chains
//  - while computing X, the other cohort's stage loads fly (counted vmcnt)
//  - no flags, no h-store ack, no poll phase on the h path
//  - consumers publish coarse progress (every 8 steps) for ring pacing
// All retries capped (fail loud, never hang).

#define T_STEPS 512
#define BATCH   64
#define DIM     512
#define UNITS   1024
#define ZCOLS   4096
#define RING    64

typedef float        f32x4 __attribute__((ext_vector_type(4)));
typedef unsigned int u32x4 __attribute__((ext_vector_type(4)));

__device__ __forceinline__ f32x4 mfma16x16x32_bf16(u32x4 a, u32x4 b, f32x4 c) {
    asm("v_mfma_f32_16x16x32_bf16 %0, %1, %2, %0" : "+v"(c) : "v"(a), "v"(b));
    return c;
}

__device__ __forceinline__ unsigned short f2bf(float f) {
    union { float f; unsigned u; } v; v.f = f;
    unsigned r = v.u + 0x7fffu + ((v.u >> 16) & 1u);   // RNE
    return (unsigned short)(r >> 16);
}

__device__ __forceinline__ float fsigmoid(float x) { return 1.0f / (1.0f + __expf(-x)); }
__device__ __forceinline__ float ftanh(float x)    { return 1.0f - 2.0f / (__expf(2.0f * x) + 1.0f); }

__device__ __forceinline__ u32x4 pack8(const float* __restrict__ p) {
    float4 f0 = reinterpret_cast<const float4*>(p)[0];
    float4 f1 = reinterpret_cast<const float4*>(p)[1];
    u32x4 r;
    r.x = (unsigned)f2bf(f0.x) | ((unsigned)f2bf(f0.y) << 16);
    r.y = (unsigned)f2bf(f0.z) | ((unsigned)f2bf(f0.w) << 16);
    r.z = (unsigned)f2bf(f1.x) | ((unsigned)f2bf(f1.y) << 16);
    r.w = (unsigned)f2bf(f1.z) | ((unsigned)f2bf(f1.w) << 16);
    return r;
}

#define LD4(d, base) \
    asm volatile("global_load_dwordx4 %0, %1, off sc0 sc1" : "=v"(d) : "v"(base));
#define LDF(d, base) \
    asm volatile("global_load_dword %0, %1, off sc0 sc1" : "=v"(d) : "v"(base));
#define LDW(d, base) \
    asm volatile("global_load_dword %0, %1, off sc0 sc1\n\ts_waitcnt vmcnt(0)" \
                 : "=v"(d) : "v"(base) : "memory");
#define STW(base, v) \
    asm volatile("global_store_dword %0, %1, off sc0 sc1" :: "v"(base), "v"(v) : "memory");
#define WAITV0 \
    asm volatile("s_waitcnt vmcnt(0)" ::: "memory"); \
    __builtin_amdgcn_sched_barrier(0);
#define WAITV1 \
    asm volatile("s_waitcnt vmcnt(1)" ::: "memory"); \
    __builtin_amdgcn_sched_barrier(0);
#define WAITV4 \
    asm volatile("s_waitcnt vmcnt(4)" ::: "memory"); \
    __builtin_amdgcn_sched_barrier(0);

// ---------------- prep kernels ----------------

__global__ void k_transpose_bf16(const float* __restrict__ in, unsigned short* __restrict__ out,
                                 int K, int N) {
    __shared__ float tile[32][33];
    int n0 = blockIdx.x * 32, k0 = blockIdx.y * 32;
    int tx = threadIdx.x, ty = threadIdx.y;
    tile[ty][tx] = in[(size_t)(k0 + ty) * N + n0 + tx];
    __syncthreads();
    out[(size_t)(n0 + ty) * K + k0 + tx] = f2bf(tile[tx][ty]);
}

__global__ void k_init(unsigned int* __restrict__ hbuf_u32,
                       unsigned int* __restrict__ prog,
                       unsigned int* __restrict__ xzflags) {
    int i = blockIdx.x * blockDim.x + threadIdx.x;            // 262144 threads
    if (i < 131072) hbuf_u32[i] = 0u;                         // [2][64][1024] u32 (tag0|h0)
    else if (i < 135168) prog[i - 131072] = 0u;               // 128 * 32 u32
    else if (i < 135680) xzflags[i - 135168] = 0u;            // [64][8]
}

// ---------------- fused producer/consumer kernel ----------------
__global__ __launch_bounds__(512, 1) void k_fused(
        const float* __restrict__ x,             // [64][512][512] f32
        const unsigned short* __restrict__ WxT,  // [4096][512] bf16
        const unsigned short* __restrict__ WhT,  // [4096][1024] bf16
        const float* __restrict__ bias,          // [4096] f32
        unsigned int* hbT,                       // [2][64][1024] u32 tagged
        float* __restrict__ out,                 // [64][1024] f32
        unsigned int* prog,                      // [128] spaced 32 u32 (coarse)
        unsigned int* xzflags,                   // [RING][8] packed u32
        float* __restrict__ xzring) {            // [RING][64][4096] f32
    __shared__ __align__(16) char smem[65536];
    const int tid  = threadIdx.x;
    const int lane = tid & 63;
    const int w    = tid >> 6;

    if (blockIdx.x < 128) {
        // ============ CONSUMER: 2-cohort pipelined recurrence ============
        char* hsA = smem;                          // 16 KB swizzled bf16 [8][1024]
        char* hsB = smem + 16384;                  // 16 KB
        float (*zb)[8][132] = (float (*)[8][132])(smem + 32768);   // [2][8][132]

        const int ct  = w & 3;                     // gate
        const int kh  = w >> 2;                    // K half
        const int mg  = blockIdx.x >> 5;
        const int zbk = blockIdx.x & 31;
        const int rA0 = mg * 16;
        const int rB0 = mg * 16 + 8;
        const int u0  = zbk * 32;
        const int c16 = lane & 15;
        const int kl  = (lane >> 4) * 8;
        const int klb = (lane >> 4) * 16;

        u32x4 breg[2][16];
        #pragma unroll
        for (int n = 0; n < 2; ++n) {
            const unsigned short* wp =
                WhT + ((size_t)(ct * UNITS + u0 + n * 16 + c16)) * UNITS + kh * 512 + kl;
            #pragma unroll
            for (int kk = 0; kk < 16; ++kk) {
                breg[n][kk] = *reinterpret_cast<const u32x4*>(wp + kk * 32);
                asm volatile("" : "+v"(breg[n][kk]));
            }
        }

        const int ri = tid >> 5;                   // 0..15 (gates use tid<256 -> 0..7)
        const int ui = tid & 31;
        float cregA = 0.0f, cregB = 0.0f;

        // stage chunk map: 4 chunks/thread, c = tid + j*512 (0..2047)
        int srow[4], scol[4];
        #pragma unroll
        for (int j = 0; j < 4; ++j) {
            int c = tid + j * 512;
            srow[j] = c >> 8;                      // 0..7
            scol[j] = (c & 255) * 4;               // u32 offset in row
        }

        unsigned int* const myprog = prog + (size_t)blockIdx.x * 32;

        // prologue: issue A(0) loads (par 0; init tags = 0 match s=0)
        u32x4 av[4], bv[4];
        #pragma unroll
        for (int j = 0; j < 4; ++j) {
            const unsigned int* p = hbT + (size_t)(rA0 + srow[j]) * UNITS + scol[j];
            LD4(av[j], p)
        }

        for (int s = 0; s < T_STEPS; ++s) {
            const unsigned par  = (unsigned)(s & 1);
            const unsigned parn = par ^ 1u;
            unsigned int* const hb_r = hbT + (size_t)par * (BATCH * UNITS);
            unsigned int* const hb_w = hbT + (size_t)parn * (BATCH * UNITS);
            const int slot = s & (RING - 1);
            const unsigned want = (unsigned)s;

            // --- [1] wait A loads (counted: gate waves may have 1 store) ---
            if (s == 0) { WAITV0 }
            else if (w < 4) { WAITV1 } else { WAITV0 }

            // --- [2] verify A tags, retry if stale ---
            {
                int it = 0;
                for (;;) {
                    bool ok =
                        (av[0].x >> 16) == want && (av[0].y >> 16) == want &&
                        (av[0].z >> 16) == want && (av[0].w >> 16) == want &&
                        (av[1].x >> 16) == want && (av[1].y >> 16) == want &&
                        (av[1].z >> 16) == want && (av[1].w >> 16) == want &&
                        (av[2].x >> 16) == want && (av[2].y >> 16) == want &&
                        (av[2].z >> 16) == want && (av[2].w >> 16) == want &&
                        (av[3].x >> 16) == want && (av[3].y >> 16) == want &&
                        (av[3].z >> 16) == want && (av[3].w >> 16) == want;
                    if (ok) break;
                    if (++it > (1 << 15)) break;
                    __builtin_amdgcn_s_sleep(1);
                    #pragma unroll
                    for (int j = 0; j < 4; ++j) {
                        const unsigned int* p = hb_r + (size_t)(rA0 + srow[j]) * UNITS + scol[j];
                        LD4(av[j], p)
                    }
                    WAITV0
                }
            }
            // --- [3] unpack A -> hsA (swizzled) ---
            #pragma unroll
            for (int j = 0; j < 4; ++j) {
                unsigned lo = (av[j].x & 0xffffu) | (av[j].y << 16);
                unsigned hi = (av[j].z & 0xffffu) | (av[j].w << 16);
                int lb = (srow[j] * 2048 + scol[j] * 2) ^ ((srow[j] & 7) << 4);
                uint2 v2; v2.x = lo; v2.y = hi;
                *reinterpret_cast<uint2*>(hsA + lb) = v2;
            }
            // --- [3.5] gate threads: issue xz-A loads (older than B loads) ---
            float xa0, xa1, xa2, xa3;
            if (tid < 256) {
                const float* xp = xzring + ((size_t)slot * BATCH + rA0 + ri) * ZCOLS + u0 + ui;
                LDF(xa0, xp) LDF(xa1, xp + UNITS) LDF(xa2, xp + 2 * UNITS) LDF(xa3, xp + 3 * UNITS)
            }
            // --- [4] issue B(s) stage loads ---
            #pragma unroll
            for (int j = 0; j < 4; ++j) {
                const unsigned int* p = hb_r + (size_t)(rB0 + srow[j]) * UNITS + scol[j];
                LD4(bv[j], p)
            }
            // --- [4.5] wave0: xz slot readiness (covers A and B this step) ---
            if (w == 0) {
                const unsigned int* fp = xzflags + (size_t)slot * 8 + (lane & 7);
                int it = 0;
                for (;;) {
                    unsigned v; LDW(v, fp)
                    bool ok = (lane < 8) ? (v == (unsigned)(s + 1)) : true;
                    if (__all((int)ok)) break;
                    if (++it > (1 << 20)) break;
                    __builtin_amdgcn_s_sleep(1);
                }
            }
            __syncthreads();                        // [5]

            // --- [6] mfma A (M=8, rows c16&7 duplicated) ---
            {
                f32x4 acc0 = {0, 0, 0, 0}, acc1 = {0, 0, 0, 0};
                asm volatile("s_nop 1" : "+v"(acc0), "+v"(acc1));
                const int arow = c16 & 7;
                #pragma unroll
                for (int kk = 0; kk < 16; ++kk) {
                    int lb = (arow * 2048 + kh * 1024 + kk * 64 + klb) ^ (arow << 4);
                    u32x4 a = *reinterpret_cast<const u32x4*>(hsA + lb);
                    acc0 = mfma16x16x32_bf16(a, breg[0][kk], acc0);
                    acc1 = mfma16x16x32_bf16(a, breg[1][kk], acc1);
                }
                asm volatile("s_nop 7\n\ts_nop 7" : "+v"(acc0), "+v"(acc1));
                if (lane < 32) {
                    const int rowq = (lane >> 4) * 4;
                    #pragma unroll
                    for (int r = 0; r < 4; ++r) {
                        zb[kh][rowq + r][ct * 32 + c16]      = acc0[r];
                        zb[kh][rowq + r][ct * 32 + 16 + c16] = acc1[r];
                    }
                }
            }
            __syncthreads();                        // [7]

            // --- [8-9] gates A (xz done via vmcnt(4): B loads are 4 newest) ---
            if (w < 4) { WAITV4 }
            if (tid < 256) {
                float zi = zb[0][ri][ui]      + zb[1][ri][ui]      + xa0;
                float zf = zb[0][ri][32 + ui] + zb[1][ri][32 + ui] + xa1;
                float zg = zb[0][ri][64 + ui] + zb[1][ri][64 + ui] + xa2;
                float zo = zb[0][ri][96 + ui] + zb[1][ri][96 + ui] + xa3;
                float ig = fsigmoid(zi), fg = fsigmoid(zf), gg = ftanh(zg), og = fsigmoid(zo);
                cregA = fg * cregA + ig * gg;
                float hn = og * ftanh(cregA);
                unsigned hv = ((unsigned)(s + 1) << 16) | (unsigned)f2bf(hn);
                unsigned int* hwp = hb_w + (size_t)(rA0 + ri) * UNITS + u0 + ui;
                STW(hwp, hv)
                if (s == T_STEPS - 1) out[(size_t)(rA0 + ri) * UNITS + u0 + ui] = hn;
            }

            // --- [10] wait + verify B tags ---
            if (w < 4) { WAITV1 } else { WAITV0 }
            {
                int it = 0;
                for (;;) {
                    bool ok =
                        (bv[0].x >> 16) == want && (bv[0].y >> 16) == want &&
                        (bv[0].z >> 16) == want && (bv[0].w >> 16) == want &&
                        (bv[1].x >> 16) == want && (bv[1].y >> 16) == want &&
                        (bv[1].z >> 16) == want && (bv[1].w >> 16) == want &&
                        (bv[2].x >> 16) == want && (bv[2].y >> 16) == want &&
                        (bv[2].z >> 16) == want && (bv[2].w >> 16) == want &&
                        (bv[3].x >> 16) == want && (bv[3].y >> 16) == want &&
                        (bv[3].z >> 16) == want && (bv[3].w >> 16) == want;
                    if (ok) break;
                    if (++it > (1 << 15)) break;
                    __builtin_amdgcn_s_sleep(1);
                    #pragma unroll
                    for (int j = 0; j < 4; ++j) {
                        const unsigned int* p = hb_r + (size_t)(rB0 + srow[j]) * UNITS + scol[j];
                        LD4(bv[j], p)
                    }
                    WAITV0
                }
            }
            // --- [11] unpack B -> hsB ---
            #pragma unroll
            for (int j = 0; j < 4; ++j) {
                unsigned lo = (bv[j].x & 0xffffu) | (bv[j].y << 16);
                unsigned hi = (bv[j].z & 0xffffu) | (bv[j].w << 16);
                int lb = (srow[j] * 2048 + scol[j] * 2) ^ ((srow[j] & 7) << 4);
                uint2 v2; v2.x = lo; v2.y = hi;
                *reinterpret_cast<uint2*>(hsB + lb) = v2;
            }
            // --- [11.5] gate threads: issue xz-B loads ---
            float xb0, xb1, xb2, xb3;
            if (tid < 256) {
                const float* xp = xzring + ((size_t)slot * BATCH + rB0 + ri) * ZCOLS + u0 + ui;
                LDF(xb0, xp) LDF(xb1, xp + UNITS) LDF(xb2, xp + 2 * UNITS) LDF(xb3, xp + 3 * UNITS)
            }
            // --- [12] issue A(s+1) loads (prefetch into next iteration) ---
            #pragma unroll
            for (int j = 0; j < 4; ++j) {
                const unsigned int* p = hb_w + (size_t)(rA0 + srow[j]) * UNITS + scol[j];
                LD4(av[j], p)
            }
            __syncthreads();                        // [13]

            // --- [14] mfma B ---
            {
                f32x4 acc0 = {0, 0, 0, 0}, acc1 = {0, 0, 0, 0};
                asm volatile("s_nop 1" : "+v"(acc0), "+v"(acc1));
                const int arow = c16 & 7;
                #pragma unroll
                for (int kk = 0; kk < 16; ++kk) {
                    int lb = (arow * 2048 + kh * 1024 + kk * 64 + klb) ^ (arow << 4);
                    u32x4 a = *reinterpret_cast<const u32x4*>(hsB + lb);
                    acc0 = mfma16x16x32_bf16(a, breg[0][kk], acc0);
                    acc1 = mfma16x16x32_bf16(a, breg[1][kk], acc1);
                }
                asm volatile("s_nop 7\n\ts_nop 7" : "+v"(acc0), "+v"(acc1));
                if (lane < 32) {
                    const int rowq = (lane >> 4) * 4;
                    #pragma unroll
                    for (int r = 0; r < 4; ++r) {
                        zb[kh][rowq + r][ct * 32 + c16]      = acc0[r];
                        zb[kh][rowq + r][ct * 32 + 16 + c16] = acc1[r];
                    }
                }
            }
            __syncthreads();                        // [15]

            // --- [16] gates B (xz-B done via vmcnt(4): A loads are 4 newest) ---
            if (w < 4) { WAITV4 }
            if (tid < 256) {
                float zi = zb[0][ri][ui]      + zb[1][ri][ui]      + xb0;
                float zf = zb[0][ri][32 + ui] + zb[1][ri][32 + ui] + xb1;
                float zg = zb[0][ri][64 + ui] + zb[1][ri][64 + ui] + xb2;
                float zo = zb[0][ri][96 + ui] + zb[1][ri][96 + ui] + xb3;
                float ig = fsigmoid(zi), fg = fsigmoid(zf), gg = ftanh(zg), og = fsigmoid(zo);
                cregB = fg * cregB + ig * gg;
                float hn = og * ftanh(cregB);
                unsigned hv = ((unsigned)(s + 1) << 16) | (unsigned)f2bf(hn);
                unsigned int* hwp = hb_w + (size_t)(rB0 + ri) * UNITS + u0 + ui;
                STW(hwp, hv)
                if (s == T_STEPS - 1) out[(size_t)(rB0 + ri) * UNITS + u0 + ui] = hn;
            }

            // --- [17] coarse progress for ring pacing ---
            if ((((s + 1) & 7) == 0) && tid == 0) {
                STW(myprog, (unsigned)(s + 1))
            }
        }
    } else {
        // ================= PRODUCER: xproj into ring (R15 verbatim) ============
        unsigned short* as_ = (unsigned short*)smem;         // 64 KB swizzled
        const int p   = blockIdx.x - 128;
        const int bx  = p & 7;               // 512-col slice
        const int jt  = p >> 3;              // t offset 0..15
        const int n0  = bx * 512 + w * 64;
        const int r16 = lane & 15;
        const int kl  = (lane >> 4) * 8;

        for (int k2 = 0; k2 < T_STEPS / 16; ++k2) {
            const int t = jt + 16 * k2;

            if (t >= RING) {
                if (w == 0) {
                    const unsigned need = (unsigned)(t - RING + 1);
                    int iter = 0;
                    for (;;) {
                        unsigned v0, v1;
                        LDW(v0, prog + (size_t)lane * 32)
                        LDW(v1, prog + (size_t)(lane + 64) * 32)
                        if (__all((int)(v0 >= need && v1 >= need))) break;
                        if (++iter > (1 << 20)) break;
                        __builtin_amdgcn_s_sleep(1);
                    }
                }
                __syncthreads();
            }

            for (int i = tid; i < 4096; i += 512) {
                int row = i >> 6, kc8 = i & 63;
                u32x4 v = pack8(x + ((size_t)row * T_STEPS + t) * DIM + kc8 * 8);
                int lb = (row * 1024 + kc8 * 16) ^ ((row & 7) << 4);
                *reinterpret_cast<u32x4*>(reinterpret_cast<char*>(as_) + lb) = v;
            }
            __syncthreads();

            const unsigned short* bp = WxT + (size_t)(n0 + r16) * DIM + kl;
            f32x4 acc[4][4] = {};
            asm volatile("s_nop 1" : "+v"(acc[0][0]), "+v"(acc[1][1]), "+v"(acc[2][2]), "+v"(acc[3][3]));
            #pragma unroll 2
            for (int kk = 0; kk < 16; ++kk) {
                u32x4 b0 = *reinterpret_cast<const u32x4*>(bp + kk * 32);
                u32x4 b1 = *reinterpret_cast<const u32x4*>(bp + 16 * DIM + kk * 32);
                u32x4 b2 = *reinterpret_cast<const u32x4*>(bp + 32 * DIM + kk * 32);
                u32x4 b3 = *reinterpret_cast<const u32x4*>(bp + 48 * DIM + kk * 32);
                u32x4 a[4];
                #pragma unroll
                for (int mt = 0; mt < 4; ++mt) {
                    int row = mt * 16 + r16;
                    int lb = (row * 1024 + (kk * 32 + kl) * 2) ^ ((row & 7) << 4);
                    a[mt] = *reinterpret_cast<const u32x4*>(reinterpret_cast<const char*>(as_) + lb);
                }
                #pragma unroll
                for (int mt = 0; mt < 4; ++mt) {
                    acc[mt][0] = mfma16x16x32_bf16(a[mt], b0, acc[mt][0]);
                    acc[mt][1] = mfma16x16x32_bf16(a[mt], b1, acc[mt][1]);
                    acc[mt][2] = mfma16x16x32_bf16(a[mt], b2, acc[mt][2]);
                    acc[mt][3] = mfma16x16x32_bf16(a[mt], b3, acc[mt][3]);
                }
            }
            asm volatile("s_nop 7\n\ts_nop 7" : "+v"(acc[0][0]), "+v"(acc[1][1]), "+v"(acc[2][2]), "+v"(acc[3][3]));

            {
                float* ringb = xzring + (size_t)(t & (RING - 1)) * BATCH * ZCOLS;
                const int rowq = (lane >> 4) * 4;
                #pragma unroll
                for (int nt = 0; nt < 4; ++nt) {
                    const int col = n0 + nt * 16 + r16;
                    const float bv = bias[col];
                    #pragma unroll
                    for (int mt = 0; mt < 4; ++mt) {
                        #pragma unroll
                        for (int r = 0; r < 4; ++r) {
                            float val = acc[mt][nt][r] + bv;
                            float* dst = ringb + (size_t)(mt * 16 + rowq + r) * ZCOLS + col;
                            asm volatile("global_store_dword %0, %1, off sc0 sc1"
                                         :: "v"(dst), "v"(val) : "memory");
                        }
                    }
                }
            }
            WAITV0
            __syncthreads();
            if (tid == 0) STW(xzflags + (size_t)(t & (RING - 1)) * 8 + bx, (unsigned)(t + 1))
            __syncthreads();
        }
    }
}

// ---------------- launch ----------------

extern "C" void kernel_launch(void* const* d_in, const int* in_sizes, int n_in,
                              void* d_out, int out_size, void* d_ws, size_t ws_size,
                              hipStream_t stream) {
    const float* x    = (const float*)d_in[0];   // [64][512][512]
    const float* Wx   = (const float*)d_in[1];   // [512][4096]
    const float* Wh   = (const float*)d_in[2];   // [1024][4096]
    const float* bias = (const float*)d_in[3];   // [4096]

    char* ws = (char*)d_ws;
    unsigned short* WxT     = (unsigned short*)(ws);                            // 4 MB
    unsigned short* WhT     = (unsigned short*)(ws + (4u << 20));               // 8 MB
    unsigned int*   hbT     = (unsigned int*)(ws + (12u << 20));                // 512 KB
    unsigned int*   prog    = (unsigned int*)(ws + (12u << 20) + (512u << 10)); // 16 KB
    unsigned int*   xzflags = (unsigned int*)(ws + (12u << 20) + (528u << 10)); // 2 KB
    float*          xzring  = (float*)(ws + (13u << 20));                       // 64 MB

    k_transpose_bf16<<<dim3(128, 16), dim3(32, 32), 0, stream>>>(Wx, WxT, 512, 4096);
    k_transpose_bf16<<<dim3(128, 32), dim3(32, 32), 0, stream>>>(Wh, WhT, 1024, 4096);
    k_init<<<512, 512, 0, stream>>>(hbT, prog, xzflags);

    k_fused<<<256, 512, 0, stream>>>(x, WxT, WhT, bias, hbT, (float*)d_out,
                                     prog, xzflags, xzring);
}

// Round 17
// 1800.340 us; speedup vs baseline: 1.1263x; 1.1263x over previous
//
#include <hip/hip_runtime.h>
#include <hip/hip_bf16.h>

// BasicLSTM: B=64, T=512, D=512, U=1024.  out = h_last [64][1024] f32.
// Round 17 = R15 with the consumer's zbuf LDS round-trip removed:
//  - Wh permuted (z-col p = u*4+g, WhP): each wave computes full K=1024
//    for 16 permuted cols (breg[32], 128 VGPR) -> no cross-wave partials
//  - 4x4 in-register transpose (4 shuffles) puts (i,f,g,o) of one unit
//    in one lane -> gates/c/h fully in registers, 3 barriers not 4
// Producers / ring / flags / poll / stage: R15 verbatim.

#define T_STEPS 512
#define BATCH   64
#define DIM     512
#define UNITS   1024
#define ZCOLS   4096
#define RING    64

typedef float        f32x4 __attribute__((ext_vector_type(4)));
typedef unsigned int u32x4 __attribute__((ext_vector_type(4)));

__device__ __forceinline__ f32x4 mfma16x16x32_bf16(u32x4 a, u32x4 b, f32x4 c) {
    asm("v_mfma_f32_16x16x32_bf16 %0, %1, %2, %0" : "+v"(c) : "v"(a), "v"(b));
    return c;
}

__device__ __forceinline__ unsigned short f2bf(float f) {
    union { float f; unsigned u; } v; v.f = f;
    unsigned r = v.u + 0x7fffu + ((v.u >> 16) & 1u);   // RNE
    return (unsigned short)(r >> 16);
}

__device__ __forceinline__ float fsigmoid(float x) { return 1.0f / (1.0f + __expf(-x)); }
__device__ __forceinline__ float ftanh(float x)    { return 1.0f - 2.0f / (__expf(2.0f * x) + 1.0f); }

__device__ __forceinline__ u32x4 pack8(const float* __restrict__ p) {
    float4 f0 = reinterpret_cast<const float4*>(p)[0];
    float4 f1 = reinterpret_cast<const float4*>(p)[1];
    u32x4 r;
    r.x = (unsigned)f2bf(f0.x) | ((unsigned)f2bf(f0.y) << 16);
    r.y = (unsigned)f2bf(f0.z) | ((unsigned)f2bf(f0.w) << 16);
    r.z = (unsigned)f2bf(f1.x) | ((unsigned)f2bf(f1.y) << 16);
    r.w = (unsigned)f2bf(f1.z) | ((unsigned)f2bf(f1.w) << 16);
    return r;
}

#define LD4(d, base) \
    asm volatile("global_load_dwordx4 %0, %1, off sc0 sc1" : "=v"(d) : "v"(base));
#define LDF(d, base) \
    asm volatile("global_load_dword %0, %1, off sc0 sc1" : "=v"(d) : "v"(base));
#define LDW(d, base) \
    asm volatile("global_load_dword %0, %1, off sc0 sc1\n\ts_waitcnt vmcnt(0)" \
                 : "=v"(d) : "v"(base) : "memory");
#define STW(base, v) \
    asm volatile("global_store_dword %0, %1, off sc0 sc1" :: "v"(base), "v"(v) : "memory");
#define STH(base, v) \
    asm volatile("global_store_short %0, %1, off sc0 sc1" :: "v"(base), "v"(v) : "memory");
#define WAITV0 \
    asm volatile("s_waitcnt vmcnt(0)" ::: "memory"); \
    __builtin_amdgcn_sched_barrier(0);

// ---------------- prep kernels ----------------

// Wx: f32 [512][4096] -> WxT bf16 [4096][512] natural (producers)
__global__ void k_transpose_bf16(const float* __restrict__ in, unsigned short* __restrict__ out,
                                 int K, int N) {
    __shared__ float tile[32][33];
    int n0 = blockIdx.x * 32, k0 = blockIdx.y * 32;
    int tx = threadIdx.x, ty = threadIdx.y;
    tile[ty][tx] = in[(size_t)(k0 + ty) * N + n0 + tx];
    __syncthreads();
    out[(size_t)(n0 + ty) * K + k0 + tx] = f2bf(tile[tx][ty]);
}

// Wh: f32 [1024][4096] -> WhP bf16 [4096][1024], row r = (c&1023)*4 + (c>>10)
__global__ void k_transpose_whp(const float* __restrict__ in, unsigned short* __restrict__ out) {
    __shared__ float tile[32][33];
    int n0 = blockIdx.x * 32, k0 = blockIdx.y * 32;
    int tx = threadIdx.x, ty = threadIdx.y;
    tile[ty][tx] = in[(size_t)(k0 + ty) * ZCOLS + n0 + tx];
    __syncthreads();
    int c = n0 + ty;
    int r = ((c & 1023) << 2) | (c >> 10);
    out[(size_t)r * UNITS + k0 + tx] = f2bf(tile[tx][ty]);
}

__global__ void k_init(unsigned int* __restrict__ hbuf_u32,
                       unsigned int* __restrict__ hflags,
                       unsigned int* __restrict__ xzflags) {
    int i = blockIdx.x * blockDim.x + threadIdx.x;
    if (i < 65536) hbuf_u32[i] = 0u;                          // [2][64][1024] bf16
    else if (i < 65536 + 4096) hflags[i - 65536] = 0u;        // 128 * 32 u32
    else if (i < 65536 + 4096 + 512) xzflags[i - 69632] = 0u; // [64][8]
}

// ---------------- fused producer/consumer kernel ----------------
__global__ __launch_bounds__(512, 1) void k_fused(
        const float* __restrict__ x,             // [64][512][512] f32
        const unsigned short* __restrict__ WxT,  // [4096][512] bf16 natural
        const unsigned short* __restrict__ WhP,  // [4096][1024] bf16 permuted
        const float* __restrict__ bias,          // [4096] f32
        unsigned short* hbuf,                    // [2][64][1024] bf16 natural
        float* __restrict__ out,                 // [64][1024] f32
        unsigned int* hflags,                    // [128] spaced 32 u32
        unsigned int* xzflags,                   // [RING][8] packed u32
        float* __restrict__ xzring) {            // [RING][64][4096] f32 natural
    __shared__ __align__(16) char smem[65536];
    const int tid  = threadIdx.x;
    const int lane = tid & 63;
    const int w    = tid >> 6;

    if (blockIdx.x < 128) {
        // ============ CONSUMER: recurrence, in-register gates ============
        char* hs = smem;                           // 32 KB swizzled [16][1024] bf16
        const int mg  = blockIdx.x >> 5;
        const int zbk = blockIdx.x & 31;
        const int r0  = mg * 16;
        const int u0  = zbk * 32;
        const int c16 = lane & 15;
        const int kl  = (lane >> 4) * 8;
        const int klb = (lane >> 4) * 16;

        // Wh slice (permuted): wave w -> WhP rows zbk*128 + w*16 + c16, full K
        u32x4 breg[32];
        {
            const unsigned short* wp =
                WhP + ((size_t)(zbk * 128 + w * 16 + c16)) * UNITS + kl;
            #pragma unroll
            for (int kk = 0; kk < 32; ++kk) {
                breg[kk] = *reinterpret_cast<const u32x4*>(wp + kk * 32);
                asm volatile("" : "+v"(breg[kk]));
            }
        }

        // per-lane output identity (after 4x4 transpose)
        const int row_l  = r0 + 4 * (lane >> 4) + (lane & 3);  // batch row
        const int unit_l = u0 + w * 4 + ((lane >> 2) & 3);     // unit (natural)
        float creg = 0.0f;

        unsigned int* const myflag = hflags + (size_t)blockIdx.x * 32;
        const unsigned int* const gflags = hflags + (size_t)mg * 32 * 32;

        // prologue: wait xz slot 0 ready
        if (w == 0) {
            const unsigned int* fp = xzflags + (lane & 7);
            int iter = 0;
            for (;;) {
                unsigned v; LDW(v, fp)
                bool ok = (lane < 8) ? (v == 1u) : true;
                if (__all((int)ok)) break;
                if (++iter > (1 << 20)) break;
                __builtin_amdgcn_s_sleep(1);
            }
        }
        __syncthreads();

        for (int s = 0; s < T_STEPS; ++s) {
            const unsigned short* hrd = hbuf + (size_t)(s & 1) * (BATCH * UNITS);
            const int slot = s & (RING - 1);

            // --- stage group h(s) -> swizzled LDS (R15 exact) ---
            {
                u32x4 sv[4];
                #pragma unroll
                for (int j = 0; j < 4; ++j) {
                    int i = tid + j * 512;
                    int row = i >> 7, kc = i & 127;
                    const unsigned short* src = hrd + (size_t)(r0 + row) * UNITS + kc * 8;
                    LD4(sv[j], src)
                }
                WAITV0
                #pragma unroll
                for (int j = 0; j < 4; ++j) {
                    int i = tid + j * 512;
                    int row = i >> 7, kc = i & 127;
                    int lb = (row * 2048 + kc * 16) ^ ((row & 7) << 4);
                    *reinterpret_cast<u32x4*>(hs + lb) = sv[j];
                }
            }
            __syncthreads();                               // [1]

            // xz loads (natural cols: gate g at g*1024 + unit_l)
            float x0, x1, x2, x3;
            {
                const float* xp = xzring + ((size_t)slot * BATCH + row_l) * ZCOLS + unit_l;
                LDF(x0, xp) LDF(x1, xp + UNITS) LDF(x2, xp + 2 * UNITS) LDF(x3, xp + 3 * UNITS)
            }

            // --- h @ WhP: full K, even/odd dual accumulators ---
            f32x4 ae = {0, 0, 0, 0}, ao = {0, 0, 0, 0};
            asm volatile("s_nop 1" : "+v"(ae), "+v"(ao));
            const int axorb = (c16 & 7) << 4;
            #pragma unroll
            for (int k2 = 0; k2 < 16; ++k2) {
                int lb0 = (c16 * 2048 + (2 * k2) * 64 + klb) ^ axorb;
                int lb1 = (c16 * 2048 + (2 * k2 + 1) * 64 + klb) ^ axorb;
                u32x4 a0 = *reinterpret_cast<const u32x4*>(hs + lb0);
                u32x4 a1 = *reinterpret_cast<const u32x4*>(hs + lb1);
                ae = mfma16x16x32_bf16(a0, breg[2 * k2], ae);
                ao = mfma16x16x32_bf16(a1, breg[2 * k2 + 1], ao);
            }
            asm volatile("s_nop 7\n\ts_nop 7" : "+v"(ae), "+v"(ao));

            // --- 4x4 transpose across 4-lane groups: lane gets (i,f,g,o) ---
            float v0, v1, v2, v3;
            {
                f32x4 zv = ae + ao;
                v0 = zv[0]; v1 = zv[1]; v2 = zv[2]; v3 = zv[3];
                // round 1 (xor 1)
                float sa = (lane & 1) ? v0 : v1;
                float sb = (lane & 1) ? v2 : v3;
                float ra = __shfl_xor(sa, 1, 64);
                float rb = __shfl_xor(sb, 1, 64);
                if (lane & 1) { v0 = ra; v2 = rb; } else { v1 = ra; v3 = rb; }
                // round 2 (xor 2)
                float sc = (lane & 2) ? v0 : v2;
                float sd = (lane & 2) ? v1 : v3;
                float rc = __shfl_xor(sc, 2, 64);
                float rd = __shfl_xor(sd, 2, 64);
                if (lane & 2) { v0 = rc; v1 = rd; } else { v2 = rc; v3 = rd; }
            }

            WAITV0    // xz loads complete

            // --- gates: fully in registers ---
            {
                float zi = v0 + x0, zf = v1 + x1, zg = v2 + x2, zo = v3 + x3;
                float ig = fsigmoid(zi), fg = fsigmoid(zf), gg = ftanh(zg), og = fsigmoid(zo);
                creg = fg * creg + ig * gg;
                float hn = og * ftanh(creg);
                unsigned hv = f2bf(hn);
                unsigned short* hwp = hbuf + (size_t)((s + 1) & 1) * (BATCH * UNITS)
                                      + (size_t)row_l * UNITS + unit_l;
                STH(hwp, hv)
                if (s == T_STEPS - 1) out[(size_t)row_l * UNITS + unit_l] = hn;
            }

            if (s < T_STEPS - 1) {
                WAITV0                        // own h stores acked (L3)
                __syncthreads();              // [2] whole block drained
                if (tid == 0) {
                    STW(myflag, (unsigned)(s + 1))
                    asm volatile("s_waitcnt vmcnt(0)" ::: "memory");
                }
                if (w == 0) {                 // combined h + xz poll (R15 exact)
                    const unsigned tgtH = (unsigned)(s + 1);
                    const unsigned tgtX = (unsigned)(s + 2);
                    const unsigned int* fp = (lane < 32)
                        ? gflags + (size_t)lane * 32
                        : xzflags + (size_t)((s + 1) & (RING - 1)) * 8 + (lane & 7);
                    int iter = 0;
                    for (;;) {
                        unsigned v; LDW(v, fp)
                        bool ok = (lane < 32) ? (v >= tgtH)
                                  : ((lane < 40) ? (v == tgtX) : true);
                        if (__all((int)ok)) break;
                        if (++iter > (1 << 20)) break;
                        __builtin_amdgcn_s_sleep(1);
                    }
                }
                __syncthreads();              // [3]
            }
        }
    } else {
        // ================= PRODUCER: xproj into ring (R15 verbatim) ============
        unsigned short* as_ = (unsigned short*)smem;         // 64 KB swizzled
        const int p   = blockIdx.x - 128;
        const int bx  = p & 7;               // 512-col slice
        const int jt  = p >> 3;              // t offset 0..15
        const int n0  = bx * 512 + w * 64;
        const int r16 = lane & 15;
        const int kl  = (lane >> 4) * 8;

        for (int k2 = 0; k2 < T_STEPS / 16; ++k2) {
            const int t = jt + 16 * k2;

            if (t >= RING) {
                if (w == 0) {
                    const unsigned need = (unsigned)(t - RING + 1);
                    int iter = 0;
                    for (;;) {
                        unsigned v0, v1;
                        LDW(v0, hflags + (size_t)lane * 32)
                        LDW(v1, hflags + (size_t)(lane + 64) * 32)
                        if (__all((int)(v0 >= need && v1 >= need))) break;
                        if (++iter > (1 << 20)) break;
                        __builtin_amdgcn_s_sleep(1);
                    }
                }
                __syncthreads();
            }

            for (int i = tid; i < 4096; i += 512) {
                int row = i >> 6, kc8 = i & 63;
                u32x4 v = pack8(x + ((size_t)row * T_STEPS + t) * DIM + kc8 * 8);
                int lb = (row * 1024 + kc8 * 16) ^ ((row & 7) << 4);
                *reinterpret_cast<u32x4*>(reinterpret_cast<char*>(as_) + lb) = v;
            }
            __syncthreads();

            const unsigned short* bp = WxT + (size_t)(n0 + r16) * DIM + kl;
            f32x4 acc[4][4] = {};
            asm volatile("s_nop 1" : "+v"(acc[0][0]), "+v"(acc[1][1]), "+v"(acc[2][2]), "+v"(acc[3][3]));
            #pragma unroll 2
            for (int kk = 0; kk < 16; ++kk) {
                u32x4 b0 = *reinterpret_cast<const u32x4*>(bp + kk * 32);
                u32x4 b1 = *reinterpret_cast<const u32x4*>(bp + 16 * DIM + kk * 32);
                u32x4 b2 = *reinterpret_cast<const u32x4*>(bp + 32 * DIM + kk * 32);
                u32x4 b3 = *reinterpret_cast<const u32x4*>(bp + 48 * DIM + kk * 32);
                u32x4 a[4];
                #pragma unroll
                for (int mt = 0; mt < 4; ++mt) {
                    int row = mt * 16 + r16;
                    int lb = (row * 1024 + (kk * 32 + kl) * 2) ^ ((row & 7) << 4);
                    a[mt] = *reinterpret_cast<const u32x4*>(reinterpret_cast<const char*>(as_) + lb);
                }
                #pragma unroll
                for (int mt = 0; mt < 4; ++mt) {
                    acc[mt][0] = mfma16x16x32_bf16(a[mt], b0, acc[mt][0]);
                    acc[mt][1] = mfma16x16x32_bf16(a[mt], b1, acc[mt][1]);
                    acc[mt][2] = mfma16x16x32_bf16(a[mt], b2, acc[mt][2]);
                    acc[mt][3] = mfma16x16x32_bf16(a[mt], b3, acc[mt][3]);
                }
            }
            asm volatile("s_nop 7\n\ts_nop 7" : "+v"(acc[0][0]), "+v"(acc[1][1]), "+v"(acc[2][2]), "+v"(acc[3][3]));

            {
                float* ringb = xzring + (size_t)(t & (RING - 1)) * BATCH * ZCOLS;
                const int rowq = (lane >> 4) * 4;
                #pragma unroll
                for (int nt = 0; nt < 4; ++nt) {
                    const int col = n0 + nt * 16 + r16;
                    const float bv = bias[col];
                    #pragma unroll
                    for (int mt = 0; mt < 4; ++mt) {
                        #pragma unroll
                        for (int r = 0; r < 4; ++r) {
                            float val = acc[mt][nt][r] + bv;
                            float* dst = ringb + (size_t)(mt * 16 + rowq + r) * ZCOLS + col;
                            asm volatile("global_store_dword %0, %1, off sc0 sc1"
                                         :: "v"(dst), "v"(val) : "memory");
                        }
                    }
                }
            }
            WAITV0
            __syncthreads();
            if (tid == 0) STW(xzflags + (size_t)(t & (RING - 1)) * 8 + bx, (unsigned)(t + 1))
            __syncthreads();
        }
    }
}

// ---------------- launch ----------------

extern "C" void kernel_launch(void* const* d_in, const int* in_sizes, int n_in,
                              void* d_out, int out_size, void* d_ws, size_t ws_size,
                              hipStream_t stream) {
    const float* x    = (const float*)d_in[0];   // [64][512][512]
    const float* Wx   = (const float*)d_in[1];   // [512][4096]
    const float* Wh   = (const float*)d_in[2];   // [1024][4096]
    const float* bias = (const float*)d_in[3];   // [4096]

    char* ws = (char*)d_ws;
    unsigned short* WxT     = (unsigned short*)(ws);                            // 4 MB
    unsigned short* WhP     = (unsigned short*)(ws + (4u << 20));               // 8 MB
    unsigned short* hbuf    = (unsigned short*)(ws + (12u << 20));              // 256 KB
    unsigned int*   hflags  = (unsigned int*)(ws + (12u << 20) + (256u << 10)); // 16 KB
    unsigned int*   xzflags = (unsigned int*)(ws + (12u << 20) + (272u << 10)); // 2 KB
    float*          xzring  = (float*)(ws + (13u << 20));                       // 64 MB

    k_transpose_bf16<<<dim3(128, 16), dim3(32, 32), 0, stream>>>(Wx, WxT, 512, 4096);
    k_transpose_whp<<<dim3(128, 32), dim3(32, 32), 0, stream>>>(Wh, WhP);
    k_init<<<160, 512, 0, stream>>>((unsigned int*)hbuf, hflags, xzflags);

    k_fused<<<256, 512, 0, stream>>>(x, WxT, WhP, bias, hbuf, (float*)d_out,
                                     hflags, xzflags, xzring);
}

// Round 18
// 1633.456 us; speedup vs baseline: 1.2413x; 1.1022x over previous
//
#include <hip/hip_runtime.h>
#include <hip/hip_bf16.h>

// BasicLSTM: B=64, T=512, D=512, U=1024.  out = h_last [64][1024] f32.
// Round 18 = R15 verbatim (best measured: 1652 us). Producer/consumer
// specialization in ONE launch:
//  blocks 0-127 : R9 recurrence (4 m-groups x 32 z-blocks), xz read from
//                 a 64-step ring via sc0sc1, readiness via 8 poll lanes.
//                 c in registers for all 512 steps.
//  blocks 128-255: xproj producers (8 col-slices x 16 t-interleave),
//                 running ahead, writing ring + flags via sc0sc1; pacing
//                 by consumer h-flags before ring-slot reuse.
// All polls capped (fail loud). Serial-latency-bound floor: 512 dependent
// grid-wide h exchanges x ~2us L3 visibility round-trip each.

#define T_STEPS 512
#define BATCH   64
#define DIM     512
#define UNITS   1024
#define ZCOLS   4096
#define MR      16
#define RING    64

typedef float        f32x4 __attribute__((ext_vector_type(4)));
typedef unsigned int u32x4 __attribute__((ext_vector_type(4)));

__device__ __forceinline__ f32x4 mfma16x16x32_bf16(u32x4 a, u32x4 b, f32x4 c) {
    asm("v_mfma_f32_16x16x32_bf16 %0, %1, %2, %0" : "+v"(c) : "v"(a), "v"(b));
    return c;
}

__device__ __forceinline__ unsigned short f2bf(float f) {
    union { float f; unsigned u; } v; v.f = f;
    unsigned r = v.u + 0x7fffu + ((v.u >> 16) & 1u);   // RNE
    return (unsigned short)(r >> 16);
}

__device__ __forceinline__ float fsigmoid(float x) { return 1.0f / (1.0f + __expf(-x)); }
__device__ __forceinline__ float ftanh(float x)    { return 1.0f - 2.0f / (__expf(2.0f * x) + 1.0f); }

__device__ __forceinline__ u32x4 pack8(const float* __restrict__ p) {
    float4 f0 = reinterpret_cast<const float4*>(p)[0];
    float4 f1 = reinterpret_cast<const float4*>(p)[1];
    u32x4 r;
    r.x = (unsigned)f2bf(f0.x) | ((unsigned)f2bf(f0.y) << 16);
    r.y = (unsigned)f2bf(f0.z) | ((unsigned)f2bf(f0.w) << 16);
    r.z = (unsigned)f2bf(f1.x) | ((unsigned)f2bf(f1.y) << 16);
    r.w = (unsigned)f2bf(f1.z) | ((unsigned)f2bf(f1.w) << 16);
    return r;
}

#define LD4(d, base) \
    asm volatile("global_load_dwordx4 %0, %1, off sc0 sc1" : "=v"(d) : "v"(base));
#define LDW(d, base) \
    asm volatile("global_load_dword %0, %1, off sc0 sc1\n\ts_waitcnt vmcnt(0)" \
                 : "=v"(d) : "v"(base) : "memory");
#define STW(base, v) \
    asm volatile("global_store_dword %0, %1, off sc0 sc1" :: "v"(base), "v"(v) : "memory");
#define WAITV0 \
    asm volatile("s_waitcnt vmcnt(0)" ::: "memory"); \
    __builtin_amdgcn_sched_barrier(0);

// ---------------- prep kernels ----------------

__global__ void k_transpose_bf16(const float* __restrict__ in, unsigned short* __restrict__ out,
                                 int K, int N) {
    __shared__ float tile[32][33];
    int n0 = blockIdx.x * 32, k0 = blockIdx.y * 32;
    int tx = threadIdx.x, ty = threadIdx.y;
    tile[ty][tx] = in[(size_t)(k0 + ty) * N + n0 + tx];
    __syncthreads();
    out[(size_t)(n0 + ty) * K + k0 + tx] = f2bf(tile[tx][ty]);
}

__global__ void k_init(unsigned int* __restrict__ hbuf_u32,
                       unsigned int* __restrict__ hflags,
                       unsigned int* __restrict__ xzflags) {
    int i = blockIdx.x * blockDim.x + threadIdx.x;           // 160*512 = 81920
    if (i < 65536) hbuf_u32[i] = 0u;                         // 2*64*1024 bf16
    else if (i < 65536 + 4096) hflags[i - 65536] = 0u;       // 128 * 32 u32
    else if (i < 65536 + 4096 + 512) xzflags[i - 69632] = 0u;// [64][8]
}

// ---------------- fused producer/consumer kernel ----------------
__global__ __launch_bounds__(512, 1) void k_fused(
        const float* __restrict__ x,             // [64][512][512] f32
        const unsigned short* __restrict__ WxT,  // [4096][512] bf16
        const unsigned short* __restrict__ WhT,  // [4096][1024] bf16
        const float* __restrict__ bias,          // [4096] f32
        unsigned short* hbuf,                    // [2][64][1024] bf16
        float* __restrict__ out,                 // [64][1024] f32
        unsigned int* hflags,                    // [128] spaced 32 u32
        unsigned int* xzflags,                   // [RING][8] packed u32
        float* __restrict__ xzring) {            // [RING][64][4096] f32
    __shared__ __align__(16) char smem[65536];
    const int tid  = threadIdx.x;
    const int lane = tid & 63;
    const int w    = tid >> 6;

    if (blockIdx.x < 128) {
        // ================= CONSUMER: R9 recurrence =================
        unsigned short* hs = (unsigned short*)smem;          // 32 KB swizzled
        float* zb = (float*)(smem + 32768);                  // [2][16][132]
        const int ct  = w & 3;
        const int kh  = w >> 2;
        const int mg  = blockIdx.x >> 5;
        const int zbk = blockIdx.x & 31;
        const int r0  = mg * MR;
        const int u0  = zbk * 32;
        const int c16 = lane & 15;
        const int kl  = (lane >> 4) * 8;
        const int klb = (lane >> 4) * 16;

        u32x4 breg[2][16];
        #pragma unroll
        for (int n = 0; n < 2; ++n) {
            const unsigned short* wp =
                WhT + ((size_t)(ct * UNITS + u0 + n * 16 + c16)) * UNITS + kh * 512 + kl;
            #pragma unroll
            for (int kk = 0; kk < 16; ++kk) {
                breg[n][kk] = *reinterpret_cast<const u32x4*>(wp + kk * 32);
                asm volatile("" : "+v"(breg[n][kk]));
            }
        }

        const int ri = tid >> 5;
        const int ui = tid & 31;
        float creg = 0.0f;

        unsigned int* const myflag = hflags + (size_t)blockIdx.x * 32;
        const unsigned int* const gflags = hflags + (size_t)mg * 32 * 32;

        // prologue: wait xz(0) ready (slot 0, all 8 col-slices == 1)
        if (w == 0) {
            const unsigned int* fp = xzflags + (lane & 7);
            int iter = 0;
            for (;;) {
                unsigned v; LDW(v, fp)
                bool ok = (lane < 8) ? (v == 1u) : true;
                if (__all((int)ok)) break;
                if (++iter > (1 << 20)) break;
                __builtin_amdgcn_s_sleep(1);
            }
        }
        __syncthreads();

        for (int s = 0; s < T_STEPS; ++s) {
            const unsigned short* hrd = hbuf + (size_t)(s & 1) * (BATCH * UNITS);

            // --- stage group h(s) -> swizzled LDS (R9 exact) ---
            {
                u32x4 sv[4];
                #pragma unroll
                for (int j = 0; j < 4; ++j) {
                    int i = tid + j * 512;
                    int row = i >> 7, kc = i & 127;
                    const unsigned short* src = hrd + (size_t)(r0 + row) * UNITS + kc * 8;
                    LD4(sv[j], src)
                }
                WAITV0
                #pragma unroll
                for (int j = 0; j < 4; ++j) {
                    int i = tid + j * 512;
                    int row = i >> 7, kc = i & 127;
                    int lb = (row * 2048 + kc * 16) ^ ((row & 7) << 4);
                    *reinterpret_cast<u32x4*>(reinterpret_cast<char*>(hs) + lb) = sv[j];
                }
            }
            __syncthreads();

            // xz loads from ring (sc0sc1; drain after MFMA)
            float xv0, xv1, xv2, xv3;
            {
                const float* xp = xzring + ((size_t)(s & (RING - 1)) * BATCH + r0 + ri) * ZCOLS
                                  + u0 + ui;
                asm volatile("global_load_dword %0, %1, off sc0 sc1" : "=v"(xv0) : "v"(xp));
                asm volatile("global_load_dword %0, %1, off sc0 sc1" : "=v"(xv1) : "v"(xp + UNITS));
                asm volatile("global_load_dword %0, %1, off sc0 sc1" : "=v"(xv2) : "v"(xp + 2 * UNITS));
                asm volatile("global_load_dword %0, %1, off sc0 sc1" : "=v"(xv3) : "v"(xp + 3 * UNITS));
            }

            // --- h @ Wh MFMA (R9 exact) ---
            f32x4 acc0 = {0, 0, 0, 0}, acc1 = {0, 0, 0, 0};
            asm volatile("s_nop 1" : "+v"(acc0), "+v"(acc1));
            const char* abase = reinterpret_cast<const char*>(hs);
            const int axor = (c16 & 7) << 4;
            #pragma unroll
            for (int kk = 0; kk < 16; ++kk) {
                int lb = (c16 * 2048 + kh * 1024 + kk * 64 + klb) ^ axor;
                u32x4 a = *reinterpret_cast<const u32x4*>(abase + lb);
                acc0 = mfma16x16x32_bf16(a, breg[0][kk], acc0);
                acc1 = mfma16x16x32_bf16(a, breg[1][kk], acc1);
            }
            asm volatile("s_nop 7\n\ts_nop 7" : "+v"(acc0), "+v"(acc1));
            {
                const int rowq = (lane >> 4) * 4;
                #pragma unroll
                for (int r = 0; r < 4; ++r) {
                    zb[((kh * 16 + rowq + r)) * 132 + ct * 32 + c16]      = acc0[r];
                    zb[((kh * 16 + rowq + r)) * 132 + ct * 32 + 16 + c16] = acc1[r];
                }
            }
            __syncthreads();
            WAITV0   // xz loads complete

            // --- gates (bias folded into ring by producers) ---
            {
                float zi = zb[ri * 132 + ui]      + zb[(16 + ri) * 132 + ui]      + xv0;
                float zf = zb[ri * 132 + 32 + ui] + zb[(16 + ri) * 132 + 32 + ui] + xv1;
                float zg = zb[ri * 132 + 64 + ui] + zb[(16 + ri) * 132 + 64 + ui] + xv2;
                float zo = zb[ri * 132 + 96 + ui] + zb[(16 + ri) * 132 + 96 + ui] + xv3;
                float ig = fsigmoid(zi), fg = fsigmoid(zf), gg = ftanh(zg), og = fsigmoid(zo);
                creg = fg * creg + ig * gg;
                float hn = og * ftanh(creg);
                unsigned hv = f2bf(hn);
                unsigned short* hwp = hbuf + (size_t)((s + 1) & 1) * (BATCH * UNITS)
                                      + (size_t)(r0 + ri) * UNITS + u0 + ui;
                asm volatile("global_store_short %0, %1, off sc0 sc1" :: "v"(hwp), "v"(hv) : "memory");
                if (s == T_STEPS - 1) out[(size_t)(r0 + ri) * UNITS + u0 + ui] = hn;
            }

            if (s < T_STEPS - 1) {
                WAITV0                        // own h stores acked (L3)
                __syncthreads();              // whole block drained
                if (tid == 0) {
                    STW(myflag, (unsigned)(s + 1))
                    asm volatile("s_waitcnt vmcnt(0)" ::: "memory");
                }
                if (w == 0) {                 // combined h + xz poll
                    const unsigned tgtH = (unsigned)(s + 1);
                    const unsigned tgtX = (unsigned)(s + 2);
                    const unsigned int* fp = (lane < 32)
                        ? gflags + (size_t)lane * 32
                        : xzflags + (size_t)((s + 1) & (RING - 1)) * 8 + (lane & 7);
                    int iter = 0;
                    for (;;) {
                        unsigned v; LDW(v, fp)
                        bool ok = (lane < 32) ? (v >= tgtH)
                                  : ((lane < 40) ? (v == tgtX) : true);
                        if (__all((int)ok)) break;
                        if (++iter > (1 << 20)) break;
                        __builtin_amdgcn_s_sleep(1);
                    }
                }
                __syncthreads();
            }
        }
    } else {
        // ================= PRODUCER: xproj into ring =================
        unsigned short* as_ = (unsigned short*)smem;         // 64 KB swizzled
        const int p   = blockIdx.x - 128;
        const int bx  = p & 7;               // 512-col slice
        const int jt  = p >> 3;              // t offset 0..15
        const int n0  = bx * 512 + w * 64;
        const int r16 = lane & 15;
        const int kl  = (lane >> 4) * 8;

        for (int k2 = 0; k2 < T_STEPS / 16; ++k2) {
            const int t = jt + 16 * k2;

            // pacing: slot reuse safe once all consumers passed t-RING
            if (t >= RING) {
                if (w == 0) {
                    const unsigned need = (unsigned)(t - RING + 1);
                    int iter = 0;
                    for (;;) {
                        unsigned v0, v1;
                        LDW(v0, hflags + (size_t)lane * 32)
                        LDW(v1, hflags + (size_t)(lane + 64) * 32)
                        if (__all((int)(v0 >= need && v1 >= need))) break;
                        if (++iter > (1 << 20)) break;
                        __builtin_amdgcn_s_sleep(1);
                    }
                }
                __syncthreads();
            }

            // stage x(:, t, :) -> packed bf16 swizzled LDS
            for (int i = tid; i < 4096; i += 512) {
                int row = i >> 6, kc8 = i & 63;
                u32x4 v = pack8(x + ((size_t)row * T_STEPS + t) * DIM + kc8 * 8);
                int lb = (row * 1024 + kc8 * 16) ^ ((row & 7) << 4);
                *reinterpret_cast<u32x4*>(reinterpret_cast<char*>(as_) + lb) = v;
            }
            __syncthreads();

            const unsigned short* bp = WxT + (size_t)(n0 + r16) * DIM + kl;
            f32x4 acc[4][4] = {};
            asm volatile("s_nop 1" : "+v"(acc[0][0]), "+v"(acc[1][1]), "+v"(acc[2][2]), "+v"(acc[3][3]));
            #pragma unroll 2
            for (int kk = 0; kk < 16; ++kk) {
                u32x4 b0 = *reinterpret_cast<const u32x4*>(bp + kk * 32);
                u32x4 b1 = *reinterpret_cast<const u32x4*>(bp + 16 * DIM + kk * 32);
                u32x4 b2 = *reinterpret_cast<const u32x4*>(bp + 32 * DIM + kk * 32);
                u32x4 b3 = *reinterpret_cast<const u32x4*>(bp + 48 * DIM + kk * 32);
                u32x4 a[4];
                #pragma unroll
                for (int mt = 0; mt < 4; ++mt) {
                    int row = mt * 16 + r16;
                    int lb = (row * 1024 + (kk * 32 + kl) * 2) ^ ((row & 7) << 4);
                    a[mt] = *reinterpret_cast<const u32x4*>(reinterpret_cast<const char*>(as_) + lb);
                }
                #pragma unroll
                for (int mt = 0; mt < 4; ++mt) {
                    acc[mt][0] = mfma16x16x32_bf16(a[mt], b0, acc[mt][0]);
                    acc[mt][1] = mfma16x16x32_bf16(a[mt], b1, acc[mt][1]);
                    acc[mt][2] = mfma16x16x32_bf16(a[mt], b2, acc[mt][2]);
                    acc[mt][3] = mfma16x16x32_bf16(a[mt], b3, acc[mt][3]);
                }
            }
            asm volatile("s_nop 7\n\ts_nop 7" : "+v"(acc[0][0]), "+v"(acc[1][1]), "+v"(acc[2][2]), "+v"(acc[3][3]));

            // write xz (+bias) to ring slot via sc0sc1
            {
                float* ringb = xzring + (size_t)(t & (RING - 1)) * BATCH * ZCOLS;
                const int rowq = (lane >> 4) * 4;
                #pragma unroll
                for (int nt = 0; nt < 4; ++nt) {
                    const int col = n0 + nt * 16 + r16;
                    const float bv = bias[col];
                    #pragma unroll
                    for (int mt = 0; mt < 4; ++mt) {
                        #pragma unroll
                        for (int r = 0; r < 4; ++r) {
                            float val = acc[mt][nt][r] + bv;
                            float* dst = ringb + (size_t)(mt * 16 + rowq + r) * ZCOLS + col;
                            asm volatile("global_store_dword %0, %1, off sc0 sc1"
                                         :: "v"(dst), "v"(val) : "memory");
                        }
                    }
                }
            }
            WAITV0
            __syncthreads();                 // whole block's slice in L3
            if (tid == 0) STW(xzflags + (size_t)(t & (RING - 1)) * 8 + bx, (unsigned)(t + 1))
            __syncthreads();
        }
    }
}

// ---------------- launch ----------------

extern "C" void kernel_launch(void* const* d_in, const int* in_sizes, int n_in,
                              void* d_out, int out_size, void* d_ws, size_t ws_size,
                              hipStream_t stream) {
    const float* x    = (const float*)d_in[0];   // [64][512][512]
    const float* Wx   = (const float*)d_in[1];   // [512][4096]
    const float* Wh   = (const float*)d_in[2];   // [1024][4096]
    const float* bias = (const float*)d_in[3];   // [4096]

    char* ws = (char*)d_ws;
    unsigned short* WxT     = (unsigned short*)(ws);                            // 4 MB
    unsigned short* WhT     = (unsigned short*)(ws + (4u << 20));               // 8 MB
    unsigned short* hbuf    = (unsigned short*)(ws + (12u << 20));              // 256 KB
    unsigned int*   hflags  = (unsigned int*)(ws + (12u << 20) + (256u << 10)); // 16 KB
    unsigned int*   xzflags = (unsigned int*)(ws + (12u << 20) + (272u << 10)); // 2 KB
    float*          xzring  = (float*)(ws + (13u << 20));                       // 64 MB

    k_transpose_bf16<<<dim3(128, 16), dim3(32, 32), 0, stream>>>(Wx, WxT, 512, 4096);
    k_transpose_bf16<<<dim3(128, 32), dim3(32, 32), 0, stream>>>(Wh, WhT, 1024, 4096);
    k_init<<<160, 512, 0, stream>>>((unsigned int*)hbuf, hflags, xzflags);

    k_fused<<<256, 512, 0, stream>>>(x, WxT, WhT, bias, hbuf, (float*)d_out,
                                     hflags, xzflags, xzring);
}